// Round 11
// baseline (368.096 us; speedup 1.0000x reference)
//
#include <hip/hip_runtime.h>
#include <math.h>

// Problem constants (from reference)
#define BG    100        // graphs
#define NPG   500        // nodes per graph (layer 1)
#define FD    128        // feature dim (F_IN == H == 128)
#define EE    600000     // edges
#define EPG   6000       // edges per graph (contiguous, never cross graphs)
#define NN    50000      // total nodes layer 1
#define K1    250
#define K2    125
#define K3    63
#define CAP   64         // max in-degree capacity (in-deg ~ Poisson(12); P(>64) ~ 1e-30)

// XCD-aligned swizzle: physical block p (round-robin over 8 XCDs via p%8) ->
// work item such that contiguous work fractions land on one XCD. Bijective.
__device__ __forceinline__ int swz(int p, int N) {
    int j = p & 7, i = p >> 3;
    int chunk = N >> 3, rem = N & 7;
    int mj = j < rem ? j : rem;
    return j * chunk + mj + i;
}

// ---------------- layer-1 CSR build: one block per graph, LDS counters ----------------
__global__ __launch_bounds__(1024) void fill_first_kernel(const int* __restrict__ ei,
                                                          int* __restrict__ deg,
                                                          int* __restrict__ col) {
    __shared__ int lcnt[NPG];
    int b = swz(blockIdx.x, BG), tid = threadIdx.x;
    for (int i = tid; i < NPG; i += 1024) lcnt[i] = 0;
    __syncthreads();
    for (int e0 = tid; e0 < EPG; e0 += 1024) {
        int e = b * EPG + e0;
        int d = ei[EE + e];
        int pos = atomicAdd(&lcnt[d - b * NPG], 1);
        if (pos < CAP) col[(long long)d * CAP + pos] = ei[e];
    }
    __syncthreads();
    for (int i = tid; i < NPG; i += 1024) deg[b * NPG + i] = lcnt[i];
}

// ---------------- gather-aggregate: mean of neighbor rows ----------------
// float4 per lane: 32 lanes per node, 2 nodes per wave. High occupancy hides the
// pointer-chase latency (8 VGPR) — do NOT fuse into the occupancy-capped GEMM
// (R6: 5x FETCH) and do NOT register-prefetch in the GEMM (R8: VGPR 140).
__global__ void gather_agg_kernel(const int* __restrict__ deg, const int* __restrict__ col,
                                  const float* __restrict__ x, float* __restrict__ mean,
                                  int n, int NB) {
    int g = swz(blockIdx.x, NB) * 256 + threadIdx.x;
    int node = g >> 5, sub = g & 31;
    if (node >= n) return;
    int d = deg[node]; if (d > CAP) d = CAP;
    const int* cp = col + (long long)node * CAP;
    float ax = 0.0f, ay = 0.0f, az = 0.0f, aw = 0.0f;
    for (int j = 0; j < d; ++j) {
        int s = cp[j];
        float4 v = ((const float4*)(x + (long long)s * FD))[sub];
        ax += v.x; ay += v.y; az += v.z; aw += v.w;
    }
    float inv = 1.0f / fmaxf((float)d, 1.0f);
    float4 o; o.x = ax * inv; o.y = ay * inv; o.z = az * inv; o.w = aw * inv;
    ((float4*)(mean + (long long)node * FD))[sub] = o;
}

// ---------------- fused SAGE GEMM + score epilogue ----------------
// h = relu(mean@Wl + x@Wr + bl); score = tanh(h.pw / ||pw||)
// 64 rows x 128 cols, 128 threads, 8x8 micro-tile (halves LDS-read instrs vs
// 4x8 — the measured pin is per-CU LDS instruction issue), 782 fine-grained
// blocks for load balance (R7's 128-row/391-block shape lost to imbalance).
// LDS ~29.5 KB -> 5 blocks/CU cap; grid gives ~3-4/CU.
__global__ __launch_bounds__(128) void sage_gemm_kernel(
        const float* __restrict__ mean, const float* __restrict__ x,
        const float* __restrict__ Wl, const float* __restrict__ Wr,
        const float* __restrict__ bl, const float* __restrict__ pw,
        float* __restrict__ hout, float* __restrict__ score, int M, int NB) {
    __shared__ __align__(16) float As[32 * 68];    // [kk][row], stride 68
    __shared__ __align__(16) float Ws[32 * 128];   // [kk][col]
    __shared__ float spart[64 * 16];
    __shared__ float snrmp[16];
    int tid  = threadIdx.x;
    int row0 = swz(blockIdx.x, NB) * 64;
    int tr   = tid >> 4;             // 0..7  -> rows 8*tr..8*tr+7
    int tc   = tid & 15;             // 0..15 -> cols {4tc..4tc+3, 64+4tc..64+4tc+3}
    float acc[8][8];
#pragma unroll
    for (int r = 0; r < 8; r++)
#pragma unroll
        for (int c = 0; c < 8; c++) acc[r][c] = 0.0f;

    int lrow  = tid >> 1;            // 0..63
    int lkoff = (tid & 1) << 4;      // 0 or 16
    int wc    = (tid & 31) << 2;     // 0..124
    int wk0   = tid >> 5;            // 0..3

    for (int kt = 0; kt < 8; ++kt) {
        bool isMean = kt < 4;
        const float* Ab = isMean ? mean : x;
        {
            int grow = row0 + lrow; if (grow > M - 1) grow = M - 1;
            const float* ar = Ab + (long long)grow * FD + (isMean ? kt : kt - 4) * 32 + lkoff;
#pragma unroll
            for (int q = 0; q < 4; ++q) {
                float4 v = *(const float4*)(ar + (q << 2));
                int kb = lkoff + (q << 2);
                As[(kb + 0) * 68 + lrow] = v.x;
                As[(kb + 1) * 68 + lrow] = v.y;
                As[(kb + 2) * 68 + lrow] = v.z;
                As[(kb + 3) * 68 + lrow] = v.w;
            }
        }
        {
            const float* WB = isMean ? Wl : Wr;
            int krow0 = (isMean ? kt : kt - 4) * 32;
#pragma unroll
            for (int q = 0; q < 8; ++q) {
                int kk = wk0 + (q << 2);
                *(float4*)&Ws[kk * 128 + wc] = *(const float4*)(WB + (long long)(krow0 + kk) * FD + wc);
            }
        }
        __syncthreads();
#pragma unroll
        for (int kk = 0; kk < 32; ++kk) {
            float4 a0 = *(const float4*)&As[kk * 68 + tr * 8];
            float4 a1 = *(const float4*)&As[kk * 68 + tr * 8 + 4];
            float4 b0 = *(const float4*)&Ws[kk * 128 + tc * 4];
            float4 b1 = *(const float4*)&Ws[kk * 128 + 64 + tc * 4];
            float av[8] = {a0.x, a0.y, a0.z, a0.w, a1.x, a1.y, a1.z, a1.w};
            float bv[8] = {b0.x, b0.y, b0.z, b0.w, b1.x, b1.y, b1.z, b1.w};
#pragma unroll
            for (int r = 0; r < 8; r++)
#pragma unroll
                for (int c = 0; c < 8; c++) acc[r][c] += av[r] * bv[c];
        }
        __syncthreads();
    }

    float4 bb0 = *(const float4*)(bl + tc * 4);
    float4 bb1 = *(const float4*)(bl + 64 + tc * 4);
    float4 w0  = *(const float4*)(pw + tc * 4);
    float4 w1  = *(const float4*)(pw + 64 + tc * 4);
    float bvec[8] = {bb0.x, bb0.y, bb0.z, bb0.w, bb1.x, bb1.y, bb1.z, bb1.w};
    float wvec[8] = {w0.x, w0.y, w0.z, w0.w, w1.x, w1.y, w1.z, w1.w};
    if (tr == 0) snrmp[tc] = w0.x*w0.x + w0.y*w0.y + w0.z*w0.z + w0.w*w0.w +
                             w1.x*w1.x + w1.y*w1.y + w1.z*w1.z + w1.w*w1.w;
#pragma unroll
    for (int r = 0; r < 8; r++) {
        int row  = tr * 8 + r;
        int grow = row0 + row;
        float h[8];
        float part = 0.0f;
#pragma unroll
        for (int c = 0; c < 8; c++) {
            h[c] = fmaxf(acc[r][c] + bvec[c], 0.0f);
            part += h[c] * wvec[c];
        }
        spart[row * 16 + tc] = part;
        if (grow < M) {
            float* dstp = hout + (long long)grow * FD;
            *(float4*)(dstp + tc * 4)      = make_float4(h[0], h[1], h[2], h[3]);
            *(float4*)(dstp + 64 + tc * 4) = make_float4(h[4], h[5], h[6], h[7]);
        }
    }
    __syncthreads();
    if (tid < 64) {
        int grow = row0 + tid;
        if (grow < M) {
            float dot = 0.0f;
#pragma unroll
            for (int i = 0; i < 16; i++) dot += spart[tid * 16 + i];
            float nr = 0.0f;
#pragma unroll
            for (int i = 0; i < 16; i++) nr += snrmp[i];
            score[grow] = tanhf(dot / sqrtf(nr));
        }
    }
}

// ---------------- fused per-graph tail: top-k sort + LDS mapping + edge remap +
// next-layer CSR fill + gather*score + readout (+ MLP head on last layer) --------
// One block per graph, 1024 threads. mode: 0 = z=, 1 = z+=, 2 = z-final + head.
__global__ __launch_bounds__(1024) void topk_tail_kernel(
        const float* __restrict__ score, const float* __restrict__ hout,
        int n_per, int k, int SN,
        float* __restrict__ xp,
        const int* __restrict__ esrc, const int* __restrict__ edst,
        const float* __restrict__ em_in,
        int* __restrict__ src_out, int* __restrict__ dst_out, float* __restrict__ em_out,
        int* __restrict__ next_deg, int* __restrict__ next_col,
        float* __restrict__ z, int mode,
        const float* __restrict__ W1, const float* __restrict__ b1,
        const float* __restrict__ W2, const float* __restrict__ b2,
        const float* __restrict__ W3, const float* __restrict__ b3,
        float* __restrict__ out) {
    __shared__ float skey[512];
    __shared__ int   sidx[512];
    __shared__ int   lmap[512];
    __shared__ int   lcnt[512];
    __shared__ float pmax[1024];
    __shared__ float psum[1024];
    __shared__ float zs[256], t1[128], t2[64], t3[16];
    int b = swz(blockIdx.x, BG), tid = threadIdx.x;

    for (int i = tid; i < SN; i += 1024) {
        if (i < n_per) { skey[i] = score[b * n_per + i]; sidx[i] = i; }
        else           { skey[i] = -INFINITY;            sidx[i] = 0x7fffffff; }
        lmap[i] = -1;
        lcnt[i] = 0;
    }
    __syncthreads();

    // bitonic sort: desc value, tie -> asc index (jax.lax.top_k order)
    for (int ks = 2; ks <= SN; ks <<= 1) {
        for (int j = ks >> 1; j > 0; j >>= 1) {
            for (int i = tid; i < SN; i += 1024) {
                int l = i ^ j;
                if (l > i) {
                    float ki = skey[i], kl = skey[l];
                    int   ii = sidx[i], il = sidx[l];
                    bool before = (ki > kl) || (ki == kl && ii < il);
                    bool up = ((i & ks) == 0);
                    if (up ? !before : before) {
                        skey[i] = kl; skey[l] = ki;
                        sidx[i] = il; sidx[l] = ii;
                    }
                }
            }
            __syncthreads();
        }
    }

    // local old->new mapping for kept nodes
    for (int i = tid; i < k; i += 1024) lmap[sidx[i]] = i;
    __syncthreads();

    // edge phase: remap this graph's edges; slot-fill next layer's CSR
    if (esrc) {
        int nbase = b * n_per, kbase = b * k;
        for (int e0 = tid; e0 < EPG; e0 += 1024) {
            int e = b * EPG + e0;
            bool alive = em_in ? (em_in[e] != 0.0f) : true;
            if (alive) {
                int ls = lmap[esrc[e] - nbase];
                int ld = lmap[edst[e] - nbase];
                bool keep = (ls >= 0) && (ld >= 0);
                if (keep) {
                    int pos = atomicAdd(&lcnt[ld], 1);
                    if (pos < CAP) next_col[(long long)(kbase + ld) * CAP + pos] = kbase + ls;
                }
                if (em_out) {
                    em_out[e]  = keep ? 1.0f : 0.0f;
                    src_out[e] = keep ? kbase + ls : 0;
                    dst_out[e] = keep ? kbase + ld : 0;
                }
            } else if (em_out) {
                em_out[e] = 0.0f; src_out[e] = 0; dst_out[e] = 0;
            }
        }
        __syncthreads();
        for (int i = tid; i < k; i += 1024) next_deg[b * k + i] = lcnt[i];
    }

    // gather + scale + readout partials: c = channel, s = row slice (8 slices)
    int c = tid & 127, s = tid >> 7;
    float mx = -INFINITY, sm = 0.0f;
    for (int r = s; r < k; r += 8) {
        long long g = (long long)(b * n_per + sidx[r]) * FD + c;
        float v = hout[g] * skey[r];
        xp[(long long)(b * k + r) * FD + c] = v;
        mx = fmaxf(mx, v); sm += v;
    }
    pmax[tid] = mx; psum[tid] = sm;
    __syncthreads();
    if (tid < 128) {
        float m = -INFINITY, su = 0.0f;
#pragma unroll
        for (int i = 0; i < 8; i++) {
            m = fmaxf(m, pmax[i * 128 + tid]);
            su += psum[i * 128 + tid];
        }
        float mean = su / (float)k;
        if (mode == 0)      { z[b * 256 + tid] = m;  z[b * 256 + 128 + tid] = mean;  }
        else if (mode == 1) { z[b * 256 + tid] += m; z[b * 256 + 128 + tid] += mean; }
        else {
            zs[tid]       = z[b * 256 + tid] + m;
            zs[128 + tid] = z[b * 256 + 128 + tid] + mean;
        }
    }
    if (mode == 2) {
        __syncthreads();
        if (tid < 128) {
            float a = b1[tid];
            for (int kk = 0; kk < 256; kk++) a += zs[kk] * W1[kk * 128 + tid];
            t1[tid] = fmaxf(a, 0.0f);
        }
        __syncthreads();
        if (tid < 64) {
            float a = b2[tid];
            for (int kk = 0; kk < 128; kk++) a += t1[kk] * W2[kk * 64 + tid];
            t2[tid] = fmaxf(a, 0.0f);
        }
        __syncthreads();
        if (tid < 10) {
            float a = b3[tid];
            for (int kk = 0; kk < 64; kk++) a += t2[kk] * W3[kk * 10 + tid];
            t3[tid] = a;
        }
        __syncthreads();
        if (tid == 0) {
            float m = -INFINITY;
            for (int i = 0; i < 10; i++) m = fmaxf(m, t3[i]);
            float su = 0.0f;
            for (int i = 0; i < 10; i++) su += expf(t3[i] - m);
            float ls = logf(su);
            for (int i = 0; i < 10; i++) out[b * 10 + i] = t3[i] - m - ls;
        }
    }
}

extern "C" void kernel_launch(void* const* d_in, const int* in_sizes, int n_in,
                              void* d_out, int out_size, void* d_ws, size_t ws_size,
                              hipStream_t stream) {
    (void)in_sizes; (void)n_in; (void)out_size; (void)ws_size;
    const float* x   = (const float*)d_in[0];
    const int*   ei  = (const int*)d_in[1];
    const float* Wl1 = (const float*)d_in[2];
    const float* bl1 = (const float*)d_in[3];
    const float* Wr1 = (const float*)d_in[4];
    const float* Wl2 = (const float*)d_in[5];
    const float* bl2 = (const float*)d_in[6];
    const float* Wr2 = (const float*)d_in[7];
    const float* Wl3 = (const float*)d_in[8];
    const float* bl3 = (const float*)d_in[9];
    const float* Wr3 = (const float*)d_in[10];
    const float* pw1 = (const float*)d_in[11];
    const float* pw2 = (const float*)d_in[12];
    const float* pw3 = (const float*)d_in[13];
    const float* W1  = (const float*)d_in[14];
    const float* b1  = (const float*)d_in[15];
    const float* W2  = (const float*)d_in[16];
    const float* b2  = (const float*)d_in[17];
    const float* W3  = (const float*)d_in[18];
    const float* b3  = (const float*)d_in[19];
    float* out = (float*)d_out;

    // workspace layout
    char* ws = (char*)d_ws;
    size_t off = 0;
    auto alloc = [&](size_t bytes) {
        char* p = ws + off;
        off = (off + bytes + 255) & ~(size_t)255;
        return p;
    };
    float* mean  = (float*)alloc((size_t)NN * FD * 4);
    float* hout  = (float*)alloc((size_t)NN * FD * 4);
    float* xp    = (float*)alloc((size_t)BG * K1 * FD * 4);
    float* sc    = (float*)alloc((size_t)NN * 4);
    int*   srcb  = (int*)  alloc((size_t)EE * 4);
    int*   dstb  = (int*)  alloc((size_t)EE * 4);
    float* emb   = (float*)alloc((size_t)EE * 4);
    int*   deg   = (int*)  alloc((size_t)NN * 4);
    int*   colb  = (int*)  alloc((size_t)NN * CAP * 4);   // 12.8 MB
    float* z     = (float*)alloc((size_t)BG * 256 * 4);

    // ================= layer 1 =================
    fill_first_kernel<<<BG, 1024, 0, stream>>>(ei, deg, colb);
    {
        int nb = (NN * 32 + 255) / 256;
        gather_agg_kernel<<<nb, 256, 0, stream>>>(deg, colb, x, mean, NN, nb);
    }
    {
        int nb = (NN + 63) / 64;
        sage_gemm_kernel<<<nb, 128, 0, stream>>>(mean, x, Wl1, Wr1, bl1, pw1, hout, sc, NN, nb);
    }
    topk_tail_kernel<<<BG, 1024, 0, stream>>>(sc, hout, NPG, K1, 512, xp,
                                              ei, ei + EE, (const float*)0,
                                              srcb, dstb, emb, deg, colb,
                                              z, 0, W1, b1, W2, b2, W3, b3, out);

    // ================= layer 2 =================
    const int N2 = BG * K1;   // 25000
    {
        int nb = (N2 * 32 + 255) / 256;
        gather_agg_kernel<<<nb, 256, 0, stream>>>(deg, colb, xp, mean, N2, nb);
    }
    {
        int nb = (N2 + 63) / 64;
        sage_gemm_kernel<<<nb, 128, 0, stream>>>(mean, xp, Wl2, Wr2, bl2, pw2, hout, sc, N2, nb);
    }
    topk_tail_kernel<<<BG, 1024, 0, stream>>>(sc, hout, K1, K2, 256, xp,
                                              srcb, dstb, emb,
                                              (int*)0, (int*)0, (float*)0, deg, colb,
                                              z, 1, W1, b1, W2, b2, W3, b3, out);

    // ================= layer 3 =================
    const int N3 = BG * K2;   // 12500
    {
        int nb = (N3 * 32 + 255) / 256;
        gather_agg_kernel<<<nb, 256, 0, stream>>>(deg, colb, xp, mean, N3, nb);
    }
    {
        int nb = (N3 + 63) / 64;
        sage_gemm_kernel<<<nb, 128, 0, stream>>>(mean, xp, Wl3, Wr3, bl3, pw3, hout, sc, N3, nb);
    }
    topk_tail_kernel<<<BG, 1024, 0, stream>>>(sc, hout, K2, K3, 128, xp,
                                              (const int*)0, (const int*)0, (const float*)0,
                                              (int*)0, (int*)0, (float*)0, (int*)0, (int*)0,
                                              z, 2, W1, b1, W2, b2, W3, b3, out);
}

// Round 12
// 316.532 us; speedup vs baseline: 1.1629x; 1.1629x over previous
//
#include <hip/hip_runtime.h>
#include <math.h>

// Problem constants (from reference)
#define BG    100        // graphs
#define NPG   500        // nodes per graph (layer 1)
#define FD    128        // feature dim (F_IN == H == 128)
#define EE    600000     // edges
#define EPG   6000       // edges per graph (contiguous, never cross graphs)
#define NN    50000      // total nodes layer 1
#define K1    250
#define K2    125
#define K3    63
#define CAP   64         // max in-degree capacity (in-deg ~ Poisson(12); P(>64) ~ 1e-30)

// XCD-aligned swizzle: physical block p (round-robin over 8 XCDs via p%8) ->
// work item such that contiguous work fractions land on one XCD. Bijective.
__device__ __forceinline__ int swz(int p, int N) {
    int j = p & 7, i = p >> 3;
    int chunk = N >> 3, rem = N & 7;
    int mj = j < rem ? j : rem;
    return j * chunk + mj + i;
}

// ---------------- layer-1 CSR build: one block per graph, LDS counters ----------------
__global__ __launch_bounds__(1024) void fill_first_kernel(const int* __restrict__ ei,
                                                          int* __restrict__ deg,
                                                          int* __restrict__ col) {
    __shared__ int lcnt[NPG];
    int b = swz(blockIdx.x, BG), tid = threadIdx.x;
    for (int i = tid; i < NPG; i += 1024) lcnt[i] = 0;
    __syncthreads();
    for (int e0 = tid; e0 < EPG; e0 += 1024) {
        int e = b * EPG + e0;
        int d = ei[EE + e];
        int pos = atomicAdd(&lcnt[d - b * NPG], 1);
        if (pos < CAP) col[(long long)d * CAP + pos] = ei[e];
    }
    __syncthreads();
    for (int i = tid; i < NPG; i += 1024) deg[b * NPG + i] = lcnt[i];
}

// ---------------- gather-aggregate: mean of neighbor rows ----------------
// 32 lanes per node (float4), 2 nodes per wave. 4-way software-pipelined
// neighbor loop: row loads for j..j+3 issue together (independent), then
// accumulate IN ORIGINAL j ORDER -> bitwise-identical sum, ~1/4 exposed latency.
// Do NOT fuse into the GEMM (R6: 5x FETCH) or register-prefetch there (R8).
__global__ void gather_agg_kernel(const int* __restrict__ deg, const int* __restrict__ col,
                                  const float* __restrict__ x, float* __restrict__ mean,
                                  int n, int NB) {
    int g = swz(blockIdx.x, NB) * 256 + threadIdx.x;
    int node = g >> 5, sub = g & 31;
    if (node >= n) return;
    int d = deg[node]; if (d > CAP) d = CAP;
    const int* cp = col + (long long)node * CAP;
    float ax = 0.0f, ay = 0.0f, az = 0.0f, aw = 0.0f;
    int j = 0;
    for (; j + 4 <= d; j += 4) {
        int s0 = cp[j], s1 = cp[j + 1], s2 = cp[j + 2], s3 = cp[j + 3];
        float4 v0 = ((const float4*)(x + (long long)s0 * FD))[sub];
        float4 v1 = ((const float4*)(x + (long long)s1 * FD))[sub];
        float4 v2 = ((const float4*)(x + (long long)s2 * FD))[sub];
        float4 v3 = ((const float4*)(x + (long long)s3 * FD))[sub];
        ax += v0.x; ay += v0.y; az += v0.z; aw += v0.w;
        ax += v1.x; ay += v1.y; az += v1.z; aw += v1.w;
        ax += v2.x; ay += v2.y; az += v2.z; aw += v2.w;
        ax += v3.x; ay += v3.y; az += v3.z; aw += v3.w;
    }
    for (; j < d; ++j) {
        float4 v = ((const float4*)(x + (long long)cp[j] * FD))[sub];
        ax += v.x; ay += v.y; az += v.z; aw += v.w;
    }
    float inv = 1.0f / fmaxf((float)d, 1.0f);
    float4 o; o.x = ax * inv; o.y = ay * inv; o.z = az * inv; o.w = aw * inv;
    ((float4*)(mean + (long long)node * FD))[sub] = o;
}

// ---------------- fused SAGE GEMM + score epilogue (R5-exact; pinned ~58 us @L1) --------
// h = relu(mean@Wl + x@Wr + bl); score = tanh(h.pw / ||pw||)
// 64x128 tile, 256 threads, 4x8 micro-tile. Pinned 58-62 us across 3 tile
// shapes + prefetch variants (R7/R8/R11) — keep this exact form.
__global__ __launch_bounds__(256) void sage_gemm_kernel(
        const float* __restrict__ mean, const float* __restrict__ x,
        const float* __restrict__ Wl, const float* __restrict__ Wr,
        const float* __restrict__ bl, const float* __restrict__ pw,
        float* __restrict__ hout, float* __restrict__ score, int M, int NB) {
    __shared__ __align__(16) float As[32 * 68];
    __shared__ __align__(16) float Ws[32 * 128];
    __shared__ float spart[64 * 16];
    __shared__ float snrmp[16];
    int tid  = threadIdx.x;
    int row0 = swz(blockIdx.x, NB) * 64;
    int tr   = tid >> 4;
    int tc   = tid & 15;
    float acc[4][8];
#pragma unroll
    for (int r = 0; r < 4; r++)
#pragma unroll
        for (int c = 0; c < 8; c++) acc[r][c] = 0.0f;

    int lrow = tid >> 3;
    int lk   = (tid & 7) * 4;

    for (int kt = 0; kt < 8; ++kt) {
        bool isMean = kt < 4;
        int kcol = (isMean ? kt * 32 : (kt - 4) * 32) + lk;
        const float* Ab = isMean ? mean : x;
#pragma unroll
        for (int p = 0; p < 2; ++p) {
            int row  = p * 32 + lrow;
            int grow = row0 + row; if (grow > M - 1) grow = M - 1;
            float4 v = *(const float4*)(Ab + (long long)grow * FD + kcol);
            As[(lk + 0) * 68 + row] = v.x;
            As[(lk + 1) * 68 + row] = v.y;
            As[(lk + 2) * 68 + row] = v.z;
            As[(lk + 3) * 68 + row] = v.w;
        }
        {
            int wc  = (tid & 31) * 4;
            int wk0 = tid >> 5;
            const float* WB = isMean ? Wl : Wr;
            int krow0 = (isMean ? kt : kt - 4) * 32;
#pragma unroll
            for (int q = 0; q < 4; ++q) {
                int kk = wk0 + q * 8;
                *(float4*)&Ws[kk * 128 + wc] = *(const float4*)(WB + (long long)(krow0 + kk) * FD + wc);
            }
        }
        __syncthreads();
#pragma unroll
        for (int kk = 0; kk < 32; ++kk) {
            float4 a  = *(const float4*)&As[kk * 68 + tr * 4];
            float4 b0 = *(const float4*)&Ws[kk * 128 + tc * 4];
            float4 b1 = *(const float4*)&Ws[kk * 128 + 64 + tc * 4];
            float av[4] = {a.x, a.y, a.z, a.w};
            float bv[8] = {b0.x, b0.y, b0.z, b0.w, b1.x, b1.y, b1.z, b1.w};
#pragma unroll
            for (int r = 0; r < 4; r++)
#pragma unroll
                for (int c = 0; c < 8; c++) acc[r][c] += av[r] * bv[c];
        }
        __syncthreads();
    }

    float4 bb0 = *(const float4*)(bl + tc * 4);
    float4 bb1 = *(const float4*)(bl + 64 + tc * 4);
    float4 w0  = *(const float4*)(pw + tc * 4);
    float4 w1  = *(const float4*)(pw + 64 + tc * 4);
    float bvec[8] = {bb0.x, bb0.y, bb0.z, bb0.w, bb1.x, bb1.y, bb1.z, bb1.w};
    float wvec[8] = {w0.x, w0.y, w0.z, w0.w, w1.x, w1.y, w1.z, w1.w};
    if (tr == 0) snrmp[tc] = w0.x*w0.x + w0.y*w0.y + w0.z*w0.z + w0.w*w0.w +
                             w1.x*w1.x + w1.y*w1.y + w1.z*w1.z + w1.w*w1.w;
#pragma unroll
    for (int r = 0; r < 4; r++) {
        int row  = tr * 4 + r;
        int grow = row0 + row;
        float h[8];
        float part = 0.0f;
#pragma unroll
        for (int c = 0; c < 8; c++) {
            h[c] = fmaxf(acc[r][c] + bvec[c], 0.0f);
            part += h[c] * wvec[c];
        }
        spart[row * 16 + tc] = part;
        if (grow < M) {
            float* dstp = hout + (long long)grow * FD;
            *(float4*)(dstp + tc * 4)      = make_float4(h[0], h[1], h[2], h[3]);
            *(float4*)(dstp + 64 + tc * 4) = make_float4(h[4], h[5], h[6], h[7]);
        }
    }
    __syncthreads();
    if (tid < 64) {
        int grow = row0 + tid;
        if (grow < M) {
            float dot = 0.0f;
#pragma unroll
            for (int i = 0; i < 16; i++) dot += spart[tid * 16 + i];
            float nr = 0.0f;
#pragma unroll
            for (int i = 0; i < 16; i++) nr += snrmp[i];
            score[grow] = tanhf(dot / sqrtf(nr));
        }
    }
}

// ---------------- fused per-graph tail: top-k sort + LDS mapping + edge remap +
// next-layer CSR fill + gather*score + readout (+ MLP head on last layer) --------
// One block per graph, 1024 threads. mode: 0 = z=, 1 = z+=, 2 = z-final + head.
// Gather/readout loop 4-way unrolled: independent hout loads batched (only
// ~1600 waves here, so exposed latency matters); adds kept in original order.
__global__ __launch_bounds__(1024) void topk_tail_kernel(
        const float* __restrict__ score, const float* __restrict__ hout,
        int n_per, int k, int SN,
        float* __restrict__ xp,
        const int* __restrict__ esrc, const int* __restrict__ edst,
        const float* __restrict__ em_in,
        int* __restrict__ src_out, int* __restrict__ dst_out, float* __restrict__ em_out,
        int* __restrict__ next_deg, int* __restrict__ next_col,
        float* __restrict__ z, int mode,
        const float* __restrict__ W1, const float* __restrict__ b1,
        const float* __restrict__ W2, const float* __restrict__ b2,
        const float* __restrict__ W3, const float* __restrict__ b3,
        float* __restrict__ out) {
    __shared__ float skey[512];
    __shared__ int   sidx[512];
    __shared__ int   lmap[512];
    __shared__ int   lcnt[512];
    __shared__ float pmax[1024];
    __shared__ float psum[1024];
    __shared__ float zs[256], t1[128], t2[64], t3[16];
    int b = swz(blockIdx.x, BG), tid = threadIdx.x;

    for (int i = tid; i < SN; i += 1024) {
        if (i < n_per) { skey[i] = score[b * n_per + i]; sidx[i] = i; }
        else           { skey[i] = -INFINITY;            sidx[i] = 0x7fffffff; }
        lmap[i] = -1;
        lcnt[i] = 0;
    }
    __syncthreads();

    // bitonic sort: desc value, tie -> asc index (jax.lax.top_k order)
    for (int ks = 2; ks <= SN; ks <<= 1) {
        for (int j = ks >> 1; j > 0; j >>= 1) {
            for (int i = tid; i < SN; i += 1024) {
                int l = i ^ j;
                if (l > i) {
                    float ki = skey[i], kl = skey[l];
                    int   ii = sidx[i], il = sidx[l];
                    bool before = (ki > kl) || (ki == kl && ii < il);
                    bool up = ((i & ks) == 0);
                    if (up ? !before : before) {
                        skey[i] = kl; skey[l] = ki;
                        sidx[i] = il; sidx[l] = ii;
                    }
                }
            }
            __syncthreads();
        }
    }

    // local old->new mapping for kept nodes
    for (int i = tid; i < k; i += 1024) lmap[sidx[i]] = i;
    __syncthreads();

    // edge phase: remap this graph's edges; slot-fill next layer's CSR
    if (esrc) {
        int nbase = b * n_per, kbase = b * k;
        for (int e0 = tid; e0 < EPG; e0 += 1024) {
            int e = b * EPG + e0;
            bool alive = em_in ? (em_in[e] != 0.0f) : true;
            if (alive) {
                int ls = lmap[esrc[e] - nbase];
                int ld = lmap[edst[e] - nbase];
                bool keep = (ls >= 0) && (ld >= 0);
                if (keep) {
                    int pos = atomicAdd(&lcnt[ld], 1);
                    if (pos < CAP) next_col[(long long)(kbase + ld) * CAP + pos] = kbase + ls;
                }
                if (em_out) {
                    em_out[e]  = keep ? 1.0f : 0.0f;
                    src_out[e] = keep ? kbase + ls : 0;
                    dst_out[e] = keep ? kbase + ld : 0;
                }
            } else if (em_out) {
                em_out[e] = 0.0f; src_out[e] = 0; dst_out[e] = 0;
            }
        }
        __syncthreads();
        for (int i = tid; i < k; i += 1024) next_deg[b * k + i] = lcnt[i];
    }

    // gather + scale + readout partials: c = channel, s = row slice (8 slices)
    int c = tid & 127, s = tid >> 7;
    float mx = -INFINITY, sm = 0.0f;
    {
        int r = s;
        long long hbase = (long long)b * n_per * FD + c;
        long long xbase = (long long)b * k * FD + c;
        for (; r + 24 < k; r += 32) {
            int i0 = sidx[r], i1 = sidx[r + 8], i2 = sidx[r + 16], i3 = sidx[r + 24];
            float k0 = skey[r], k1 = skey[r + 8], k2 = skey[r + 16], k3 = skey[r + 24];
            float v0 = hout[hbase + (long long)i0 * FD] * k0;
            float v1 = hout[hbase + (long long)i1 * FD] * k1;
            float v2 = hout[hbase + (long long)i2 * FD] * k2;
            float v3 = hout[hbase + (long long)i3 * FD] * k3;
            xp[xbase + (long long)(r)      * FD] = v0;
            xp[xbase + (long long)(r + 8)  * FD] = v1;
            xp[xbase + (long long)(r + 16) * FD] = v2;
            xp[xbase + (long long)(r + 24) * FD] = v3;
            mx = fmaxf(mx, v0); sm += v0;
            mx = fmaxf(mx, v1); sm += v1;
            mx = fmaxf(mx, v2); sm += v2;
            mx = fmaxf(mx, v3); sm += v3;
        }
        for (; r < k; r += 8) {
            float v = hout[hbase + (long long)sidx[r] * FD] * skey[r];
            xp[xbase + (long long)r * FD] = v;
            mx = fmaxf(mx, v); sm += v;
        }
    }
    pmax[tid] = mx; psum[tid] = sm;
    __syncthreads();
    if (tid < 128) {
        float m = -INFINITY, su = 0.0f;
#pragma unroll
        for (int i = 0; i < 8; i++) {
            m = fmaxf(m, pmax[i * 128 + tid]);
            su += psum[i * 128 + tid];
        }
        float mean = su / (float)k;
        if (mode == 0)      { z[b * 256 + tid] = m;  z[b * 256 + 128 + tid] = mean;  }
        else if (mode == 1) { z[b * 256 + tid] += m; z[b * 256 + 128 + tid] += mean; }
        else {
            zs[tid]       = z[b * 256 + tid] + m;
            zs[128 + tid] = z[b * 256 + 128 + tid] + mean;
        }
    }
    if (mode == 2) {
        __syncthreads();
        if (tid < 128) {
            float a = b1[tid];
            for (int kk = 0; kk < 256; kk++) a += zs[kk] * W1[kk * 128 + tid];
            t1[tid] = fmaxf(a, 0.0f);
        }
        __syncthreads();
        if (tid < 64) {
            float a = b2[tid];
            for (int kk = 0; kk < 128; kk++) a += t1[kk] * W2[kk * 64 + tid];
            t2[tid] = fmaxf(a, 0.0f);
        }
        __syncthreads();
        if (tid < 10) {
            float a = b3[tid];
            for (int kk = 0; kk < 64; kk++) a += t2[kk] * W3[kk * 10 + tid];
            t3[tid] = a;
        }
        __syncthreads();
        if (tid == 0) {
            float m = -INFINITY;
            for (int i = 0; i < 10; i++) m = fmaxf(m, t3[i]);
            float su = 0.0f;
            for (int i = 0; i < 10; i++) su += expf(t3[i] - m);
            float ls = logf(su);
            for (int i = 0; i < 10; i++) out[b * 10 + i] = t3[i] - m - ls;
        }
    }
}

extern "C" void kernel_launch(void* const* d_in, const int* in_sizes, int n_in,
                              void* d_out, int out_size, void* d_ws, size_t ws_size,
                              hipStream_t stream) {
    (void)in_sizes; (void)n_in; (void)out_size; (void)ws_size;
    const float* x   = (const float*)d_in[0];
    const int*   ei  = (const int*)d_in[1];
    const float* Wl1 = (const float*)d_in[2];
    const float* bl1 = (const float*)d_in[3];
    const float* Wr1 = (const float*)d_in[4];
    const float* Wl2 = (const float*)d_in[5];
    const float* bl2 = (const float*)d_in[6];
    const float* Wr2 = (const float*)d_in[7];
    const float* Wl3 = (const float*)d_in[8];
    const float* bl3 = (const float*)d_in[9];
    const float* Wr3 = (const float*)d_in[10];
    const float* pw1 = (const float*)d_in[11];
    const float* pw2 = (const float*)d_in[12];
    const float* pw3 = (const float*)d_in[13];
    const float* W1  = (const float*)d_in[14];
    const float* b1  = (const float*)d_in[15];
    const float* W2  = (const float*)d_in[16];
    const float* b2  = (const float*)d_in[17];
    const float* W3  = (const float*)d_in[18];
    const float* b3  = (const float*)d_in[19];
    float* out = (float*)d_out;

    // workspace layout
    char* ws = (char*)d_ws;
    size_t off = 0;
    auto alloc = [&](size_t bytes) {
        char* p = ws + off;
        off = (off + bytes + 255) & ~(size_t)255;
        return p;
    };
    float* mean  = (float*)alloc((size_t)NN * FD * 4);
    float* hout  = (float*)alloc((size_t)NN * FD * 4);
    float* xp    = (float*)alloc((size_t)BG * K1 * FD * 4);
    float* sc    = (float*)alloc((size_t)NN * 4);
    int*   srcb  = (int*)  alloc((size_t)EE * 4);
    int*   dstb  = (int*)  alloc((size_t)EE * 4);
    float* emb   = (float*)alloc((size_t)EE * 4);
    int*   deg   = (int*)  alloc((size_t)NN * 4);
    int*   colb  = (int*)  alloc((size_t)NN * CAP * 4);   // 12.8 MB
    float* z     = (float*)alloc((size_t)BG * 256 * 4);

    // ================= layer 1 =================
    fill_first_kernel<<<BG, 1024, 0, stream>>>(ei, deg, colb);
    {
        int nb = (NN * 32 + 255) / 256;
        gather_agg_kernel<<<nb, 256, 0, stream>>>(deg, colb, x, mean, NN, nb);
    }
    {
        int nb = (NN + 63) / 64;
        sage_gemm_kernel<<<nb, 256, 0, stream>>>(mean, x, Wl1, Wr1, bl1, pw1, hout, sc, NN, nb);
    }
    topk_tail_kernel<<<BG, 1024, 0, stream>>>(sc, hout, NPG, K1, 512, xp,
                                              ei, ei + EE, (const float*)0,
                                              srcb, dstb, emb, deg, colb,
                                              z, 0, W1, b1, W2, b2, W3, b3, out);

    // ================= layer 2 =================
    const int N2 = BG * K1;   // 25000
    {
        int nb = (N2 * 32 + 255) / 256;
        gather_agg_kernel<<<nb, 256, 0, stream>>>(deg, colb, xp, mean, N2, nb);
    }
    {
        int nb = (N2 + 63) / 64;
        sage_gemm_kernel<<<nb, 256, 0, stream>>>(mean, xp, Wl2, Wr2, bl2, pw2, hout, sc, N2, nb);
    }
    topk_tail_kernel<<<BG, 1024, 0, stream>>>(sc, hout, K1, K2, 256, xp,
                                              srcb, dstb, emb,
                                              (int*)0, (int*)0, (float*)0, deg, colb,
                                              z, 1, W1, b1, W2, b2, W3, b3, out);

    // ================= layer 3 =================
    const int N3 = BG * K2;   // 12500
    {
        int nb = (N3 * 32 + 255) / 256;
        gather_agg_kernel<<<nb, 256, 0, stream>>>(deg, colb, xp, mean, N3, nb);
    }
    {
        int nb = (N3 + 63) / 64;
        sage_gemm_kernel<<<nb, 256, 0, stream>>>(mean, xp, Wl3, Wr3, bl3, pw3, hout, sc, N3, nb);
    }
    topk_tail_kernel<<<BG, 1024, 0, stream>>>(sc, hout, K2, K3, 128, xp,
                                              (const int*)0, (const int*)0, (const float*)0,
                                              (int*)0, (int*)0, (float*)0, (int*)0, (int*)0,
                                              z, 2, W1, b1, W2, b2, W3, b3, out);
}